// Round 1
// baseline (1150.893 us; speedup 1.0000x reference)
//
#include <hip/hip_runtime.h>
#include <math.h>

#define B 4
#define T1 16
#define T2 16
#define SEG 4
#define V 8000
#define E 256
#define H 256
#define ENC 512
#define EOS 2
#define NEGV -1e30f
#define G4 (4*H)                  // 1024 gates
#define NCELL (B*T1*(T2+1))       // 1088
#define LCPB 4                    // cells per block, lstm kernel
#define FCPB 8                    // cells per block, fc kernel
#define VS 8                      // vocab splits in fc kernel
#define VSPAN (V/VS)              // 1000

// ---------- weight transposes (k-major for coalesced loads) ----------
__global__ void k_transpose(const float* __restrict__ in, float* __restrict__ out, int R, int K) {
    int idx = blockIdx.x * 256 + threadIdx.x;
    if (idx >= R * K) return;
    int r = idx / K, k = idx % K;
    out[(size_t)k * R + r] = in[idx];
}

// w_ih0 (4H, H+E): split into ctx part (cols 0..H-1) and x part (cols H..H+E-1), both transposed
__global__ void k_split_wih0(const float* __restrict__ w, float* __restrict__ ctxT, float* __restrict__ xT) {
    int idx = blockIdx.x * 256 + threadIdx.x;
    if (idx >= G4 * (H + E)) return;
    int g = idx / (H + E), k = idx % (H + E);
    float v = w[idx];
    if (k < H) ctxT[(size_t)k * G4 + g] = v;
    else       xT[(size_t)(k - H) * G4 + g] = v;
}

// ---------- h0/c0 = eo @ projT + b ----------
__global__ void k_init_state(const float* __restrict__ enc, const float* __restrict__ phT,
                             const float* __restrict__ phb, const float* __restrict__ pcT,
                             const float* __restrict__ pcb, float* __restrict__ h0, float* __restrict__ c0) {
    __shared__ float eo[ENC];
    int bi = blockIdx.x;            // b*T1 + i
    int b = bi / T1, i = bi % T1;
    int j = threadIdx.x;            // 0..255
    for (int e = j; e < ENC; e += 256) eo[e] = enc[(size_t)(i * B + b) * ENC + e];
    __syncthreads();
    float ha = phb[j], ca = pcb[j];
    for (int e = 0; e < ENC; ++e) {
        float x = eo[e];
        ha += x * phT[(size_t)e * H + j];
        ca += x * pcT[(size_t)e * H + j];
    }
    h0[(size_t)bi * H + j] = ha;
    c0[(size_t)bi * H + j] = ca;
}

// broadcast h0/c0 into per-cell state, zero layer-2 state
__global__ void k_bcast_init(const float* __restrict__ h0, const float* __restrict__ c0,
                             float* __restrict__ h1, float* __restrict__ c1,
                             float* __restrict__ h2, float* __restrict__ c2) {
    int cell = blockIdx.x;
    int bi = cell / (T2 + 1);
    int j = threadIdx.x;
    h1[(size_t)cell * H + j] = h0[(size_t)bi * H + j];
    c1[(size_t)cell * H + j] = c0[(size_t)bi * H + j];
    h2[(size_t)cell * H + j] = 0.f;
    c2[(size_t)cell * H + j] = 0.f;
}

// pre_ctx[bi][g] = b0[g] + sum_k h0[bi][k] * w_ih0[g][k]   (ctx columns)
__global__ void k_prectx(const float* __restrict__ h0, const float* __restrict__ ctxT,
                         const float* __restrict__ b0, float* __restrict__ pre_ctx) {
    __shared__ float hr[H];
    int bi = blockIdx.x;
    int j = threadIdx.x;
    hr[j] = h0[(size_t)bi * H + j];
    __syncthreads();
    float a0 = b0[j], a1 = b0[H + j], a2 = b0[2 * H + j], a3 = b0[3 * H + j];
    for (int k = 0; k < H; ++k) {
        float x = hr[k];
        const float* w = ctxT + (size_t)k * G4;
        a0 += x * w[j]; a1 += x * w[H + j]; a2 += x * w[2 * H + j]; a3 += x * w[3 * H + j];
    }
    float* o = pre_ctx + (size_t)bi * G4;
    o[j] = a0; o[H + j] = a1; o[2 * H + j] = a2; o[3 * H + j] = a3;
}

// pre_x[(s,b,t)][g] = sum_k x_s[b,t][k] * w_ih0[g][H+k]
__global__ void k_prex(const int* __restrict__ y, const float* __restrict__ embed,
                       const float* __restrict__ start_embed, const float* __restrict__ xT,
                       float* __restrict__ pre_x) {
    __shared__ float xr[E];
    int row = blockIdx.x;                 // (s*B + b)*(T2+1) + t
    int s = row / (B * (T2 + 1));
    int rem = row % (B * (T2 + 1));
    int b = rem / (T2 + 1), t = rem % (T2 + 1);
    int j = threadIdx.x;
    const float* src;
    if (s == 0) src = start_embed;
    else {
        int tt = t + s - 1; if (tt > T2 - 1) tt = T2 - 1;
        src = embed + (size_t)y[b * T2 + tt] * E;
    }
    xr[j] = src[j];
    __syncthreads();
    float a0 = 0, a1 = 0, a2 = 0, a3 = 0;
    for (int k = 0; k < E; ++k) {
        float x = xr[k];
        const float* w = xT + (size_t)k * G4;
        a0 += x * w[j]; a1 += x * w[H + j]; a2 += x * w[2 * H + j]; a3 += x * w[3 * H + j];
    }
    float* o = pre_x + (size_t)row * G4;
    o[j] = a0; o[H + j] = a1; o[2 * H + j] = a2; o[3 * H + j] = a3;
}

__device__ __forceinline__ float sigm(float x) { return 1.f / (1.f + __expf(-x)); }

// fused 2-layer LSTM step for LCPB cells per block
__global__ void k_lstm_step(int s, const float* __restrict__ pre_ctx, const float* __restrict__ pre_x,
                            const float* __restrict__ whh0T, const float* __restrict__ wih1T,
                            const float* __restrict__ whh1T, const float* __restrict__ b1g,
                            float* __restrict__ h1, float* __restrict__ c1,
                            float* __restrict__ h2, float* __restrict__ c2) {
    __shared__ float h1r[LCPB][H];
    __shared__ float h2r[LCPB][H];
    int j = threadIdx.x;
    int cell0 = blockIdx.x * LCPB;
    for (int idx = j; idx < LCPB * H; idx += 256) {
        int c = idx >> 8, k = idx & 255;
        h1r[c][k] = h1[(size_t)(cell0 + c) * H + k];
        h2r[c][k] = h2[(size_t)(cell0 + c) * H + k];
    }
    __syncthreads();
    float a0[LCPB], a1[LCPB], a2[LCPB], a3[LCPB];
#pragma unroll
    for (int c = 0; c < LCPB; ++c) {
        int cell = cell0 + c;
        int bi = cell / (T2 + 1);
        int b = bi / T1;
        int t = cell % (T2 + 1);
        int prow = (s * B + b) * (T2 + 1) + t;
        const float* pc = pre_ctx + (size_t)bi * G4;
        const float* px = pre_x + (size_t)prow * G4;
        a0[c] = pc[j] + px[j];
        a1[c] = pc[H + j] + px[H + j];
        a2[c] = pc[2 * H + j] + px[2 * H + j];
        a3[c] = pc[3 * H + j] + px[3 * H + j];
    }
    for (int k = 0; k < H; ++k) {
        const float* w = whh0T + (size_t)k * G4;
        float w0 = w[j], w1 = w[H + j], w2 = w[2 * H + j], w3 = w[3 * H + j];
#pragma unroll
        for (int c = 0; c < LCPB; ++c) {
            float hv = h1r[c][k];
            a0[c] += hv * w0; a1[c] += hv * w1; a2[c] += hv * w2; a3[c] += hv * w3;
        }
    }
    float hn[LCPB];
#pragma unroll
    for (int c = 0; c < LCPB; ++c) {
        int cell = cell0 + c;
        float ig = sigm(a0[c]);
        float fg = sigm(a1[c]);
        float gg = tanhf(a2[c]);
        float og = sigm(a3[c]);
        float cn = fg * c1[(size_t)cell * H + j] + ig * gg;
        hn[c] = og * tanhf(cn);
        c1[(size_t)cell * H + j] = cn;
        h1[(size_t)cell * H + j] = hn[c];
    }
    __syncthreads();
#pragma unroll
    for (int c = 0; c < LCPB; ++c) h1r[c][j] = hn[c];
    __syncthreads();
    // layer 1
#pragma unroll
    for (int c = 0; c < LCPB; ++c) {
        a0[c] = b1g[j]; a1[c] = b1g[H + j]; a2[c] = b1g[2 * H + j]; a3[c] = b1g[3 * H + j];
    }
    for (int k = 0; k < H; ++k) {
        const float* wa = wih1T + (size_t)k * G4;
        const float* wb = whh1T + (size_t)k * G4;
        float wa0 = wa[j], wa1 = wa[H + j], wa2 = wa[2 * H + j], wa3 = wa[3 * H + j];
        float wb0 = wb[j], wb1 = wb[H + j], wb2 = wb[2 * H + j], wb3 = wb[3 * H + j];
#pragma unroll
        for (int c = 0; c < LCPB; ++c) {
            float hv = h1r[c][k], gv = h2r[c][k];
            a0[c] += hv * wa0 + gv * wb0;
            a1[c] += hv * wa1 + gv * wb1;
            a2[c] += hv * wa2 + gv * wb2;
            a3[c] += hv * wa3 + gv * wb3;
        }
    }
#pragma unroll
    for (int c = 0; c < LCPB; ++c) {
        int cell = cell0 + c;
        float ig = sigm(a0[c]);
        float fg = sigm(a1[c]);
        float gg = tanhf(a2[c]);
        float og = sigm(a3[c]);
        float cn = fg * c2[(size_t)cell * H + j] + ig * gg;
        float hh = og * tanhf(cn);
        c2[(size_t)cell * H + j] = cn;
        h2[(size_t)cell * H + j] = hh;
    }
}

// fc + online logsumexp partials; grid (NCELL/FCPB, VS)
__global__ void k_fc(int s, const float* __restrict__ h2, const float* __restrict__ fcwT,
                     const float* __restrict__ fcb, const int* __restrict__ y,
                     float* __restrict__ pm, float* __restrict__ ps,
                     float* __restrict__ tl, float* __restrict__ el) {
    __shared__ float h2s[FCPB][H];
    __shared__ float wm[FCPB][4], wsum[FCPB][4];
    __shared__ int tgtv[FCPB];
    int tid = threadIdx.x;
    int cell0 = blockIdx.x * FCPB;
    int split = blockIdx.y;
    int vstart = split * VSPAN;
    for (int idx = tid; idx < FCPB * H; idx += 256) {
        int c = idx >> 8, k = idx & 255;
        h2s[c][k] = h2[(size_t)(cell0 + c) * H + k];
    }
    if (tid < FCPB) {
        int cell = cell0 + tid;
        int b = cell / (T1 * (T2 + 1));
        int t = cell % (T2 + 1);
        int tv = 0;
        if (s < SEG) { int tt = t + s; if (tt > T2 - 1) tt = T2 - 1; tv = y[b * T2 + tt]; }
        tgtv[tid] = tv;
    }
    __syncthreads();

    int vl[4];
    float acc[4][FCPB];
#pragma unroll
    for (int q = 0; q < 4; ++q) {
        int x = vstart + q * 256 + tid;
        vl[q] = (x < V) ? x : (V - 1);
        float fb = fcb[vl[q]];
#pragma unroll
        for (int c = 0; c < FCPB; ++c) acc[q][c] = fb;
    }
    for (int k = 0; k < H; ++k) {
        const float* w = fcwT + (size_t)k * V;
        float w0 = w[vl[0]], w1 = w[vl[1]], w2 = w[vl[2]], w3 = w[vl[3]];
#pragma unroll
        for (int c = 0; c < FCPB; ++c) {
            float hv = h2s[c][k];
            acc[0][c] += hv * w0; acc[1][c] += hv * w1; acc[2][c] += hv * w2; acc[3][c] += hv * w3;
        }
    }
    float m[FCPB], sm[FCPB];
#pragma unroll
    for (int c = 0; c < FCPB; ++c) { m[c] = -3.4e38f; sm[c] = 0.f; }
#pragma unroll
    for (int q = 0; q < 4; ++q) {
        if (q * 256 + tid < VSPAN) {
            int x = vstart + q * 256 + tid;
#pragma unroll
            for (int c = 0; c < FCPB; ++c) {
                float val = acc[q][c];
                float M = fmaxf(m[c], val);
                sm[c] = sm[c] * __expf(m[c] - M) + __expf(val - M);
                m[c] = M;
                if (x == tgtv[c]) tl[cell0 + c] = val;
                if (x == EOS)     el[cell0 + c] = val;
            }
        }
    }
    int lane = tid & 63, wv = tid >> 6;
#pragma unroll
    for (int c = 0; c < FCPB; ++c) {
        float mm = m[c], ss = sm[c];
        for (int off = 32; off > 0; off >>= 1) {
            float om = __shfl_down(mm, off);
            float os = __shfl_down(ss, off);
            float M = fmaxf(mm, om);
            ss = ss * __expf(mm - M) + os * __expf(om - M);
            mm = M;
        }
        if (lane == 0) { wm[c][wv] = mm; wsum[c][wv] = ss; }
    }
    __syncthreads();
    if (tid < FCPB) {
        float mm = wm[tid][0], ss = wsum[tid][0];
        for (int w2i = 1; w2i < 4; ++w2i) {
            float om = wm[tid][w2i], os = wsum[tid][w2i];
            float M = fmaxf(mm, om);
            ss = ss * __expf(mm - M) + os * __expf(om - M);
            mm = M;
        }
        pm[(size_t)(cell0 + tid) * VS + split] = mm;
        ps[(size_t)(cell0 + tid) * VS + split] = ss;
    }
}

// combine vocab-split partials into sel/eosp
__global__ void k_fc_combine(int s, const float* __restrict__ pm, const float* __restrict__ ps,
                             const float* __restrict__ tl, const float* __restrict__ el,
                             float* __restrict__ sel, float* __restrict__ eosp) {
    int cell = blockIdx.x * 256 + threadIdx.x;
    if (cell >= NCELL) return;
    float m = pm[(size_t)cell * VS], sm = ps[(size_t)cell * VS];
    for (int v = 1; v < VS; ++v) {
        float om = pm[(size_t)cell * VS + v], os = ps[(size_t)cell * VS + v];
        float M = fmaxf(m, om);
        sm = sm * __expf(m - M) + os * __expf(om - M);
        m = M;
    }
    float lse = m + __logf(sm);
    sel[s * NCELL + cell] = tl[cell] - lse;
    eosp[s * NCELL + cell] = el[cell] - lse;
}

// final DP over (T1) steps; single block
__global__ void k_dp(const float* __restrict__ sel, const float* __restrict__ eosp, float* __restrict__ out) {
    __shared__ float alpha[B][T2 + 1];
    int tid = threadIdx.x;
    int b = tid / (T2 + 1), t = tid % (T2 + 1);
    bool act = tid < B * (T2 + 1);
    if (act) alpha[b][t] = (t == 0) ? 0.f : NEGV;
    __syncthreads();
    for (int i = 0; i < T1; ++i) {
        float val = NEGV;
        if (act) {
            float terms[SEG + 1];
            float mx = -3.4e38f;
            int cnt = 0;
            for (int j = 0; j <= SEG && j <= t; ++j) {
                int tp = t - j;
                int cell = (b * T1 + i) * (T2 + 1) + tp;
                float cum = 0.f;
                for (int s2 = 0; s2 < j; ++s2) cum += sel[s2 * NCELL + cell];
                float term = alpha[b][tp] + cum + eosp[j * NCELL + cell];
                terms[cnt++] = term;
                mx = fmaxf(mx, term);
            }
            float ssum = 0.f;
            for (int q = 0; q < cnt; ++q) ssum += __expf(terms[q] - mx);
            val = mx + __logf(ssum);
        }
        __syncthreads();
        if (act) alpha[b][t] = val;
        __syncthreads();
    }
    if (act && t == T2) out[b] = alpha[b][T2];
}

extern "C" void kernel_launch(void* const* d_in, const int* in_sizes, int n_in,
                              void* d_out, int out_size, void* d_ws, size_t ws_size,
                              hipStream_t stream) {
    const int*   y     = (const int*)d_in[0];
    const float* enc   = (const float*)d_in[1];
    const float* embed = (const float*)d_in[2];
    const float* se    = (const float*)d_in[3];
    const float* phw   = (const float*)d_in[4];
    const float* phb   = (const float*)d_in[5];
    const float* pcw   = (const float*)d_in[6];
    const float* pcb   = (const float*)d_in[7];
    const float* wih0  = (const float*)d_in[8];
    const float* whh0  = (const float*)d_in[9];
    const float* b0    = (const float*)d_in[10];
    const float* wih1  = (const float*)d_in[11];
    const float* whh1  = (const float*)d_in[12];
    const float* b1    = (const float*)d_in[13];
    const float* fcw   = (const float*)d_in[14];
    const float* fcb   = (const float*)d_in[15];

    float* ws = (float*)d_ws;
    size_t off = 0;
    auto alloc = [&](size_t n) { float* p = ws + off; off += n; return p; };
    float* projhT  = alloc((size_t)ENC * H);
    float* projcT  = alloc((size_t)ENC * H);
    float* ctxT    = alloc((size_t)H * G4);
    float* xT      = alloc((size_t)E * G4);
    float* whh0T   = alloc((size_t)H * G4);
    float* wih1T   = alloc((size_t)H * G4);
    float* whh1T   = alloc((size_t)H * G4);
    float* fcwT    = alloc((size_t)H * V);
    float* h0      = alloc((size_t)B * T1 * H);
    float* c0      = alloc((size_t)B * T1 * H);
    float* h1      = alloc((size_t)NCELL * H);
    float* c1      = alloc((size_t)NCELL * H);
    float* h2      = alloc((size_t)NCELL * H);
    float* c2      = alloc((size_t)NCELL * H);
    float* pre_ctx = alloc((size_t)B * T1 * G4);
    float* pre_x   = alloc((size_t)(SEG + 1) * B * (T2 + 1) * G4);
    float* selbuf  = alloc((size_t)(SEG + 1) * NCELL);
    float* eospbuf = alloc((size_t)(SEG + 1) * NCELL);
    float* pm      = alloc((size_t)NCELL * VS);
    float* ps      = alloc((size_t)NCELL * VS);
    float* tl      = alloc((size_t)NCELL);
    float* el      = alloc((size_t)NCELL);

    hipLaunchKernelGGL(k_transpose, dim3((H * ENC + 255) / 256), dim3(256), 0, stream, phw, projhT, H, ENC);
    hipLaunchKernelGGL(k_transpose, dim3((H * ENC + 255) / 256), dim3(256), 0, stream, pcw, projcT, H, ENC);
    hipLaunchKernelGGL(k_split_wih0, dim3((G4 * (H + E) + 255) / 256), dim3(256), 0, stream, wih0, ctxT, xT);
    hipLaunchKernelGGL(k_transpose, dim3((G4 * H + 255) / 256), dim3(256), 0, stream, whh0, whh0T, G4, H);
    hipLaunchKernelGGL(k_transpose, dim3((G4 * H + 255) / 256), dim3(256), 0, stream, wih1, wih1T, G4, H);
    hipLaunchKernelGGL(k_transpose, dim3((G4 * H + 255) / 256), dim3(256), 0, stream, whh1, whh1T, G4, H);
    hipLaunchKernelGGL(k_transpose, dim3((V * H + 255) / 256), dim3(256), 0, stream, fcw, fcwT, V, H);

    hipLaunchKernelGGL(k_init_state, dim3(B * T1), dim3(256), 0, stream, enc, projhT, phb, projcT, pcb, h0, c0);
    hipLaunchKernelGGL(k_bcast_init, dim3(NCELL), dim3(256), 0, stream, h0, c0, h1, c1, h2, c2);
    hipLaunchKernelGGL(k_prectx, dim3(B * T1), dim3(256), 0, stream, h0, ctxT, b0, pre_ctx);
    hipLaunchKernelGGL(k_prex, dim3((SEG + 1) * B * (T2 + 1)), dim3(256), 0, stream, y, embed, se, xT, pre_x);

    for (int s = 0; s <= SEG; ++s) {
        hipLaunchKernelGGL(k_lstm_step, dim3(NCELL / LCPB), dim3(256), 0, stream,
                           s, pre_ctx, pre_x, whh0T, wih1T, whh1T, b1, h1, c1, h2, c2);
        hipLaunchKernelGGL(k_fc, dim3(NCELL / FCPB, VS), dim3(256), 0, stream,
                           s, h2, fcwT, fcb, y, pm, ps, tl, el);
        hipLaunchKernelGGL(k_fc_combine, dim3((NCELL + 255) / 256), dim3(256), 0, stream,
                           s, pm, ps, tl, el, selbuf, eospbuf);
    }
    hipLaunchKernelGGL(k_dp, dim3(1), dim3(128), 0, stream, selbuf, eospbuf, (float*)d_out);
}

// Round 2
// 659.604 us; speedup vs baseline: 1.7448x; 1.7448x over previous
//
#include <hip/hip_runtime.h>
#include <math.h>

#define B 4
#define T1 16
#define T2 16
#define SEG 4
#define V 8000
#define E 256
#define H 256
#define ENC 512
#define EOS 2
#define NEGV -1e30f
#define G4 (4*H)                  // 1024 gates
#define NCELL (B*T1*(T2+1))       // 1088
#define NBV (V/64)                // 125 vocab blocks in fc kernel

typedef __attribute__((ext_vector_type(4))) float f32x4;
typedef __attribute__((ext_vector_type(8))) short bf16x8;

__device__ __forceinline__ float sigm(float x) { return 1.f / (1.f + __expf(-x)); }
__device__ __forceinline__ float b2f(short x) {
    unsigned u = ((unsigned)(unsigned short)x) << 16;
    return __builtin_bit_cast(float, u);
}
__device__ __forceinline__ short f2b(float f) {
    unsigned u = __builtin_bit_cast(unsigned, f);
    unsigned r = (u + 0x7fffu + ((u >> 16) & 1u)) >> 16;
    return (short)r;
}

// ---------- setup kernels ----------
__global__ void k_transpose(const float* __restrict__ in, float* __restrict__ out, int R, int K) {
    int idx = blockIdx.x * 256 + threadIdx.x;
    if (idx >= R * K) return;
    int r = idx / K, k = idx % K;
    out[(size_t)k * R + r] = in[idx];
}

__global__ void k_split_wih0(const float* __restrict__ w, float* __restrict__ ctxT, float* __restrict__ xT) {
    int idx = blockIdx.x * 256 + threadIdx.x;
    if (idx >= G4 * (H + E)) return;
    int g = idx / (H + E), k = idx % (H + E);
    float v = w[idx];
    if (k < H) ctxT[(size_t)k * G4 + g] = v;
    else       xT[(size_t)(k - H) * G4 + g] = v;
}

__global__ void k_cast(const float* __restrict__ in, short* __restrict__ out, int n) {
    int i = blockIdx.x * 256 + threadIdx.x;
    if (i < n) out[i] = f2b(in[i]);
}

// pack [wih1 | whh1] into (1024, 512) bf16
__global__ void k_pack_w1(const float* __restrict__ wih1, const float* __restrict__ whh1, short* __restrict__ w1cat) {
    int i = blockIdx.x * 256 + threadIdx.x;
    if (i >= 1024 * 512) return;
    int g = i >> 9, k = i & 511;
    float v = (k < 256) ? wih1[(size_t)g * 256 + k] : whh1[(size_t)g * 256 + (k - 256)];
    w1cat[i] = f2b(v);
}

// ---------- h0/c0 = eo @ projT + b ----------
__global__ void k_init_state(const float* __restrict__ enc, const float* __restrict__ phT,
                             const float* __restrict__ phb, const float* __restrict__ pcT,
                             const float* __restrict__ pcb, float* __restrict__ h0, float* __restrict__ c0) {
    __shared__ float eo[ENC];
    int bi = blockIdx.x;
    int b = bi / T1, i = bi % T1;
    int j = threadIdx.x;
    for (int e = j; e < ENC; e += 256) eo[e] = enc[(size_t)(i * B + b) * ENC + e];
    __syncthreads();
    float ha = phb[j], ca = pcb[j];
    for (int e = 0; e < ENC; ++e) {
        float x = eo[e];
        ha += x * phT[(size_t)e * H + j];
        ca += x * pcT[(size_t)e * H + j];
    }
    h0[(size_t)bi * H + j] = ha;
    c0[(size_t)bi * H + j] = ca;
}

// per-cell init: c1=c0, c2=0, hcat=[bf16(h0) | 0]
__global__ void k_bcast_init(const float* __restrict__ h0, const float* __restrict__ c0,
                             float* __restrict__ c1, float* __restrict__ c2, short* __restrict__ hcat) {
    int cell = blockIdx.x;
    int bi = cell / (T2 + 1);
    int j = threadIdx.x;
    c1[(size_t)cell * H + j] = c0[(size_t)bi * H + j];
    c2[(size_t)cell * H + j] = 0.f;
    hcat[(size_t)cell * 512 + j] = f2b(h0[(size_t)bi * H + j]);
    hcat[(size_t)cell * 512 + 256 + j] = 0;
}

// pre_ctx[bi][g] = b0[g] + sum_k h0[bi][k] * w_ih0[g][k]
__global__ void k_prectx(const float* __restrict__ h0, const float* __restrict__ ctxT,
                         const float* __restrict__ b0, float* __restrict__ pre_ctx) {
    __shared__ float hr[H];
    int bi = blockIdx.x;
    int j = threadIdx.x;
    hr[j] = h0[(size_t)bi * H + j];
    __syncthreads();
    float a0 = b0[j], a1 = b0[H + j], a2 = b0[2 * H + j], a3 = b0[3 * H + j];
    for (int k = 0; k < H; ++k) {
        float x = hr[k];
        const float* w = ctxT + (size_t)k * G4;
        a0 += x * w[j]; a1 += x * w[H + j]; a2 += x * w[2 * H + j]; a3 += x * w[3 * H + j];
    }
    float* o = pre_ctx + (size_t)bi * G4;
    o[j] = a0; o[H + j] = a1; o[2 * H + j] = a2; o[3 * H + j] = a3;
}

// pre_x[(s,b,t)][g] = sum_k x_s[b,t][k] * w_ih0[g][H+k]
__global__ void k_prex(const int* __restrict__ y, const float* __restrict__ embed,
                       const float* __restrict__ start_embed, const float* __restrict__ xT,
                       float* __restrict__ pre_x) {
    __shared__ float xr[E];
    int row = blockIdx.x;
    int s = row / (B * (T2 + 1));
    int rem = row % (B * (T2 + 1));
    int b = rem / (T2 + 1), t = rem % (T2 + 1);
    int j = threadIdx.x;
    const float* src;
    if (s == 0) src = start_embed;
    else {
        int tt = t + s - 1; if (tt > T2 - 1) tt = T2 - 1;
        src = embed + (size_t)y[b * T2 + tt] * E;
    }
    xr[j] = src[j];
    __syncthreads();
    float a0 = 0, a1 = 0, a2 = 0, a3 = 0;
    for (int k = 0; k < E; ++k) {
        float x = xr[k];
        const float* w = xT + (size_t)k * G4;
        a0 += x * w[j]; a1 += x * w[H + j]; a2 += x * w[2 * H + j]; a3 += x * w[3 * H + j];
    }
    float* o = pre_x + (size_t)row * G4;
    o[j] = a0; o[H + j] = a1; o[2 * H + j] = a2; o[3 * H + j] = a3;
}

// ---------- generic MFMA GEMM: out[m][n] = sum_k A[m][k] * Bw[n][k] ----------
// grid (M/64, N/64), block 256 (4 waves), wave computes 16M x 64N
__global__ void k_gemm_gates(const short* __restrict__ A, int lda, int K,
                             const short* __restrict__ Bw,
                             float* __restrict__ outp, int ldo) {
    int wave = threadIdx.x >> 6, lane = threadIdx.x & 63;
    int ln = lane & 15, kg = lane >> 4;
    int m0 = blockIdx.x * 64 + wave * 16;
    int n0 = blockIdx.y * 64;
    const short* Ap = A + (size_t)(m0 + ln) * lda + kg * 8;
    const short* Bp = Bw + (size_t)(n0 + ln) * K + kg * 8;
    f32x4 acc[4] = {};
    for (int k = 0; k < K; k += 32) {
        bf16x8 a = *(const bf16x8*)(Ap + k);
#pragma unroll
        for (int nf = 0; nf < 4; ++nf) {
            bf16x8 b = *(const bf16x8*)(Bp + (size_t)nf * 16 * K + k);
            acc[nf] = __builtin_amdgcn_mfma_f32_16x16x32_bf16(a, b, acc[nf], 0, 0, 0);
        }
    }
#pragma unroll
    for (int nf = 0; nf < 4; ++nf)
#pragma unroll
        for (int r = 0; r < 4; ++r)
            outp[(size_t)(m0 + kg * 4 + r) * ldo + n0 + nf * 16 + ln] = acc[nf][r];
}

// ---------- layer-0 nonlinearity ----------
__global__ void k_elem0(int s, const float* __restrict__ gates, const float* __restrict__ pre_ctx,
                        const float* __restrict__ pre_x, float* __restrict__ c1, short* __restrict__ hcat) {
    int cell = blockIdx.x; int j = threadIdx.x;
    int bi = cell / (T2 + 1);
    int b = bi / T1; int t = cell % (T2 + 1);
    int prow = (s * B + b) * (T2 + 1) + t;
    const float* g0 = gates + (size_t)cell * G4;
    const float* pc = pre_ctx + (size_t)bi * G4;
    const float* px = pre_x + (size_t)prow * G4;
    float ig = g0[j]         + pc[j]         + px[j];
    float fg = g0[256 + j]   + pc[256 + j]   + px[256 + j];
    float gg = g0[512 + j]   + pc[512 + j]   + px[512 + j];
    float og = g0[768 + j]   + pc[768 + j]   + px[768 + j];
    float cn = sigm(fg) * c1[(size_t)cell * H + j] + sigm(ig) * tanhf(gg);
    float hn = sigm(og) * tanhf(cn);
    c1[(size_t)cell * H + j] = cn;
    hcat[(size_t)cell * 512 + j] = f2b(hn);
}

// ---------- layer-1 nonlinearity ----------
__global__ void k_elem1(const float* __restrict__ gates, const float* __restrict__ b1,
                        float* __restrict__ c2, short* __restrict__ hcat) {
    int cell = blockIdx.x; int j = threadIdx.x;
    const float* g0 = gates + (size_t)cell * G4;
    float ig = g0[j]       + b1[j];
    float fg = g0[256 + j] + b1[256 + j];
    float gg = g0[512 + j] + b1[512 + j];
    float og = g0[768 + j] + b1[768 + j];
    float cn = sigm(fg) * c2[(size_t)cell * H + j] + sigm(ig) * tanhf(gg);
    float hn = sigm(og) * tanhf(cn);
    c2[(size_t)cell * H + j] = cn;
    hcat[(size_t)cell * 512 + 256 + j] = f2b(hn);
}

// ---------- fc GEMM + fused online LSE partials ----------
// grid (NCELL/64, NBV), block 256; h2bf = hcat + 256 col offset, lda = 512
__global__ void k_fc_mfma(const short* __restrict__ h2bf, const short* __restrict__ Wv,
                          const float* __restrict__ fcb,
                          float* __restrict__ pm, float* __restrict__ ps) {
    int wave = threadIdx.x >> 6, lane = threadIdx.x & 63;
    int ln = lane & 15, kg = lane >> 4;
    int m0 = blockIdx.x * 64 + wave * 16;
    int n0 = blockIdx.y * 64;
    const short* Ap = h2bf + (size_t)(m0 + ln) * 512 + kg * 8;
    const short* Bp = Wv + (size_t)(n0 + ln) * 256 + kg * 8;
    f32x4 acc[4] = {};
    for (int k = 0; k < 256; k += 32) {
        bf16x8 a = *(const bf16x8*)(Ap + k);
#pragma unroll
        for (int nf = 0; nf < 4; ++nf) {
            bf16x8 b = *(const bf16x8*)(Bp + (size_t)nf * 16 * 256 + k);
            acc[nf] = __builtin_amdgcn_mfma_f32_16x16x32_bf16(a, b, acc[nf], 0, 0, 0);
        }
    }
    float m_[4], s_[4];
#pragma unroll
    for (int r = 0; r < 4; ++r) { m_[r] = -3.4e38f; s_[r] = 0.f; }
#pragma unroll
    for (int nf = 0; nf < 4; ++nf) {
        float fb = fcb[n0 + nf * 16 + ln];
#pragma unroll
        for (int r = 0; r < 4; ++r) {
            float v = acc[nf][r] + fb;
            float M = fmaxf(m_[r], v);
            s_[r] = s_[r] * __expf(m_[r] - M) + __expf(v - M);
            m_[r] = M;
        }
    }
#pragma unroll
    for (int mask = 1; mask < 16; mask <<= 1) {
#pragma unroll
        for (int r = 0; r < 4; ++r) {
            float om = __shfl_xor(m_[r], mask);
            float os = __shfl_xor(s_[r], mask);
            float M = fmaxf(m_[r], om);
            s_[r] = s_[r] * __expf(m_[r] - M) + os * __expf(om - M);
            m_[r] = M;
        }
    }
    if (ln == 0) {
#pragma unroll
        for (int r = 0; r < 4; ++r) {
            int cell = m0 + kg * 4 + r;
            pm[(size_t)blockIdx.y * NCELL + cell] = m_[r];
            ps[(size_t)blockIdx.y * NCELL + cell] = s_[r];
        }
    }
}

// ---------- tgt / EOS logits: 1 wave per cell ----------
__global__ void k_tgt(int s, const short* __restrict__ h2bf, const short* __restrict__ Wv,
                      const float* __restrict__ fcb, const int* __restrict__ y,
                      float* __restrict__ tl, float* __restrict__ el) {
    int cell = blockIdx.x; int lane = threadIdx.x;
    int b = cell / (T1 * (T2 + 1)); int t = cell % (T2 + 1);
    int tv = 0;
    if (s < SEG) { int tt = t + s; if (tt > T2 - 1) tt = T2 - 1; tv = y[b * T2 + tt]; }
    const short* a  = h2bf + (size_t)cell * 512;
    const short* w1 = Wv + (size_t)tv * 256;
    const short* w2 = Wv + (size_t)EOS * 256;
    float s1 = 0.f, s2 = 0.f;
    int k0 = lane * 4;
#pragma unroll
    for (int q = 0; q < 4; ++q) {
        float av = b2f(a[k0 + q]);
        s1 += av * b2f(w1[k0 + q]);
        s2 += av * b2f(w2[k0 + q]);
    }
    for (int off = 32; off > 0; off >>= 1) {
        s1 += __shfl_down(s1, off);
        s2 += __shfl_down(s2, off);
    }
    if (lane == 0) {
        tl[cell] = s1 + fcb[tv];
        el[cell] = s2 + fcb[EOS];
    }
}

// ---------- combine LSE partials -> sel / eosp ----------
__global__ void k_combine(int s, const float* __restrict__ pm, const float* __restrict__ ps,
                          const float* __restrict__ tl, const float* __restrict__ el,
                          float* __restrict__ sel, float* __restrict__ eosp) {
    int cell = blockIdx.x * 256 + threadIdx.x;
    if (cell >= NCELL) return;
    float m = -3.4e38f, sm = 0.f;
    for (int v2 = 0; v2 < NBV; ++v2) {
        float om = pm[(size_t)v2 * NCELL + cell], os = ps[(size_t)v2 * NCELL + cell];
        float M = fmaxf(m, om);
        sm = sm * __expf(m - M) + os * __expf(om - M);
        m = M;
    }
    float lse = m + __logf(sm);
    sel[s * NCELL + cell] = tl[cell] - lse;
    eosp[s * NCELL + cell] = el[cell] - lse;
}

// ---------- final DP ----------
__global__ void k_dp(const float* __restrict__ sel, const float* __restrict__ eosp, float* __restrict__ out) {
    __shared__ float alpha[B][T2 + 1];
    int tid = threadIdx.x;
    int b = tid / (T2 + 1), t = tid % (T2 + 1);
    bool act = tid < B * (T2 + 1);
    if (act) alpha[b][t] = (t == 0) ? 0.f : NEGV;
    __syncthreads();
    for (int i = 0; i < T1; ++i) {
        float val = NEGV;
        if (act) {
            float terms[SEG + 1];
            float mx = -3.4e38f;
            int cnt = 0;
            for (int j = 0; j <= SEG && j <= t; ++j) {
                int tp = t - j;
                int cell = (b * T1 + i) * (T2 + 1) + tp;
                float cum = 0.f;
                for (int s2 = 0; s2 < j; ++s2) cum += sel[s2 * NCELL + cell];
                float term = alpha[b][tp] + cum + eosp[j * NCELL + cell];
                terms[cnt++] = term;
                mx = fmaxf(mx, term);
            }
            float ssum = 0.f;
            for (int q = 0; q < cnt; ++q) ssum += __expf(terms[q] - mx);
            val = mx + __logf(ssum);
        }
        __syncthreads();
        if (act) alpha[b][t] = val;
        __syncthreads();
    }
    if (act && t == T2) out[b] = alpha[b][T2];
}

extern "C" void kernel_launch(void* const* d_in, const int* in_sizes, int n_in,
                              void* d_out, int out_size, void* d_ws, size_t ws_size,
                              hipStream_t stream) {
    const int*   y     = (const int*)d_in[0];
    const float* enc   = (const float*)d_in[1];
    const float* embed = (const float*)d_in[2];
    const float* se    = (const float*)d_in[3];
    const float* phw   = (const float*)d_in[4];
    const float* phb   = (const float*)d_in[5];
    const float* pcw   = (const float*)d_in[6];
    const float* pcb   = (const float*)d_in[7];
    const float* wih0  = (const float*)d_in[8];
    const float* whh0  = (const float*)d_in[9];
    const float* b0    = (const float*)d_in[10];
    const float* wih1  = (const float*)d_in[11];
    const float* whh1  = (const float*)d_in[12];
    const float* b1    = (const float*)d_in[13];
    const float* fcw   = (const float*)d_in[14];
    const float* fcb   = (const float*)d_in[15];

    float* ws = (float*)d_ws;
    size_t off = 0;
    auto alloc = [&](size_t n) { float* p = ws + off; off += n; return p; };
    float* projhT  = alloc((size_t)ENC * H);
    float* projcT  = alloc((size_t)ENC * H);
    float* ctxT    = alloc((size_t)H * G4);
    float* xT      = alloc((size_t)E * G4);
    float* h0      = alloc((size_t)B * T1 * H);
    float* c0      = alloc((size_t)B * T1 * H);
    float* pre_ctx = alloc((size_t)B * T1 * G4);
    float* pre_x   = alloc((size_t)(SEG + 1) * B * (T2 + 1) * G4);
    float* c1      = alloc((size_t)NCELL * H);
    float* c2      = alloc((size_t)NCELL * H);
    float* gates   = alloc((size_t)NCELL * G4);
    float* selbuf  = alloc((size_t)(SEG + 1) * NCELL);
    float* eospbuf = alloc((size_t)(SEG + 1) * NCELL);
    float* pm      = alloc((size_t)128 * NCELL);
    float* ps      = alloc((size_t)128 * NCELL);
    float* tl      = alloc((size_t)NCELL);
    float* el      = alloc((size_t)NCELL);
    short* hcat    = (short*)alloc((size_t)NCELL * 512 / 2);
    short* whh0bf  = (short*)alloc((size_t)G4 * H / 2);
    short* w1cat   = (short*)alloc((size_t)G4 * 512 / 2);
    short* fcwbf   = (short*)alloc((size_t)V * H / 2);

    hipLaunchKernelGGL(k_transpose, dim3((H * ENC + 255) / 256), dim3(256), 0, stream, phw, projhT, H, ENC);
    hipLaunchKernelGGL(k_transpose, dim3((H * ENC + 255) / 256), dim3(256), 0, stream, pcw, projcT, H, ENC);
    hipLaunchKernelGGL(k_split_wih0, dim3((G4 * (H + E) + 255) / 256), dim3(256), 0, stream, wih0, ctxT, xT);
    hipLaunchKernelGGL(k_cast, dim3((G4 * H + 255) / 256), dim3(256), 0, stream, whh0, whh0bf, G4 * H);
    hipLaunchKernelGGL(k_pack_w1, dim3((G4 * 512 + 255) / 256), dim3(256), 0, stream, wih1, whh1, w1cat);
    hipLaunchKernelGGL(k_cast, dim3((V * H + 255) / 256), dim3(256), 0, stream, fcw, fcwbf, V * H);

    hipLaunchKernelGGL(k_init_state, dim3(B * T1), dim3(256), 0, stream, enc, projhT, phb, projcT, pcb, h0, c0);
    hipLaunchKernelGGL(k_bcast_init, dim3(NCELL), dim3(256), 0, stream, h0, c0, c1, c2, hcat);
    hipLaunchKernelGGL(k_prectx, dim3(B * T1), dim3(256), 0, stream, h0, ctxT, b0, pre_ctx);
    hipLaunchKernelGGL(k_prex, dim3((SEG + 1) * B * (T2 + 1)), dim3(256), 0, stream, y, embed, se, xT, pre_x);

    for (int s = 0; s <= SEG; ++s) {
        // layer 0: gates = h1_prev @ whh0^T
        hipLaunchKernelGGL(k_gemm_gates, dim3(NCELL / 64, G4 / 64), dim3(256), 0, stream,
                           hcat, 512, 256, whh0bf, gates, G4);
        hipLaunchKernelGGL(k_elem0, dim3(NCELL), dim3(256), 0, stream, s, gates, pre_ctx, pre_x, c1, hcat);
        // layer 1: gates = [h1_new | h2_prev] @ [wih1 | whh1]^T
        hipLaunchKernelGGL(k_gemm_gates, dim3(NCELL / 64, G4 / 64), dim3(256), 0, stream,
                           hcat, 512, 512, w1cat, gates, G4);
        hipLaunchKernelGGL(k_elem1, dim3(NCELL), dim3(256), 0, stream, gates, b1, c2, hcat);
        // fc + LSE
        hipLaunchKernelGGL(k_fc_mfma, dim3(NCELL / 64, NBV), dim3(256), 0, stream,
                           hcat + 256, fcwbf, fcb, pm, ps);
        hipLaunchKernelGGL(k_tgt, dim3(NCELL), dim3(64), 0, stream, s, hcat + 256, fcwbf, fcb, y, tl, el);
        hipLaunchKernelGGL(k_combine, dim3((NCELL + 255) / 256), dim3(256), 0, stream,
                           s, pm, ps, tl, el, selbuf, eospbuf);
    }
    hipLaunchKernelGGL(k_dp, dim3(1), dim3(128), 0, stream, selbuf, eospbuf, (float*)d_out);
}